// Round 5
// baseline (245.424 us; speedup 1.0000x reference)
//
#include <hip/hip_runtime.h>

#define NUM_NODES 100000
#define P 8
#define NPART 12500             // NUM_NODES / P
#define GAMMA 0.5f

// Native vector types for nontemporal builtins (HIP int4/float4 are structs
// and are rejected by __builtin_nontemporal_*).
typedef int   nint4  __attribute__((ext_vector_type(4)));
typedef float nfloat4 __attribute__((ext_vector_type(4)));

// 32-bit packed partial: bits [31:22] = count (max 1023), bits [21:0] =
// fixed-point sum, scale 2^14. mask in [0,1), per-chunk node degree ~1.
#define SCALE 16384.0f
#define INV_SCALE (1.0f / 16384.0f)
#define CNT_ONE (1u << 22)
#define SUM_MASK ((1u << 22) - 1)

// ---------- main path: partitioned LDS scatter, no global atomics ----------

// XCD-aware mapping: dispatcher assigns consecutive blockIdx round-robin
// across the 8 XCDs. We want all 8 partition-blocks of a chunk on the SAME
// XCD so they share its L2 copy of the chunk stream:
//   xcd = g & 7, j = g >> 3, cpx = C/8
//   c = xcd*cpx + j%cpx, p = j/cpx
__global__ void part_scatter_kernel(const float* __restrict__ mask,
                                    const int* __restrict__ src,
                                    unsigned* __restrict__ partials,
                                    int E, int CS, int C) {
    __shared__ unsigned tab[NPART];
    const int g = blockIdx.x;
    const int cpx = C >> 3;               // chunks per XCD
    const int xcd = g & 7;
    const int j = g >> 3;
    const int c = xcd * cpx + (j % cpx);
    const int p = j / cpx;
    const int pbase = p * NPART;

    for (int t = threadIdx.x; t < NPART; t += blockDim.x) tab[t] = 0u;
    __syncthreads();

    const int start = c * CS;             // CS % 4 == 0 -> 16B-aligned int4
    const int end = min(E, start + CS);
    const int nquads = (end - start) >> 2;

    for (int q = threadIdx.x; q < nquads; q += blockDim.x) {
        const int i = start + q * 4;
        nint4 s = *(const nint4*)(src + i);
        nfloat4 m = *(const nfloat4*)(mask + i);
        int sx = s.x - pbase;
        if ((unsigned)sx < NPART) atomicAdd(&tab[sx], CNT_ONE | (unsigned)(m.x * SCALE + 0.5f));
        int sy = s.y - pbase;
        if ((unsigned)sy < NPART) atomicAdd(&tab[sy], CNT_ONE | (unsigned)(m.y * SCALE + 0.5f));
        int sz = s.z - pbase;
        if ((unsigned)sz < NPART) atomicAdd(&tab[sz], CNT_ONE | (unsigned)(m.z * SCALE + 0.5f));
        int sw = s.w - pbase;
        if ((unsigned)sw < NPART) atomicAdd(&tab[sw], CNT_ONE | (unsigned)(m.w * SCALE + 0.5f));
    }
    for (int i = start + nquads * 4 + threadIdx.x; i < end; i += blockDim.x) {
        int sx = src[i] - pbase;
        if ((unsigned)sx < NPART)
            atomicAdd(&tab[sx], CNT_ONE | (unsigned)(mask[i] * SCALE + 0.5f));
    }

    __syncthreads();
    // write at LOGICAL (c,p) index so reduce_avg layout is mapping-agnostic;
    // nontemporal: written once, read once by reduce_avg.
    unsigned* dstp = partials + ((size_t)c * P + p) * NPART;
    for (int t = threadIdx.x; t < NPART; t += blockDim.x)
        __builtin_nontemporal_store(tab[t], dstp + t);
}

// K2: reduce C partials per node, finalize mean with clamp(count, min=1).
__global__ void reduce_avg_kernel(const unsigned* __restrict__ partials,
                                  float* __restrict__ avg,
                                  int C) {
    int n = blockIdx.x * blockDim.x + threadIdx.x;
    if (n < NUM_NODES) {
        int p = n / NPART;
        int loc = n - p * NPART;
        const unsigned* base = partials + (size_t)p * NPART + loc;
        unsigned cnt = 0, sum = 0;
        const size_t stride = (size_t)P * NPART;
        for (int c = 0; c < C; ++c) {
            unsigned v = __builtin_nontemporal_load(base + (size_t)c * stride);
            cnt += v >> 22;
            sum += v & SUM_MASK;
        }
        avg[n] = ((float)sum * INV_SCALE) / fmaxf((float)cnt, 1.0f);
    }
}

// K3: gather endpoint means, blend with original mask. Streams are
// nontemporal so they don't evict the L2-resident avg table (400 KB);
// the avg gathers stay cacheable.
__global__ void smooth_kernel(const float* __restrict__ mask,
                              const int* __restrict__ src,
                              const int* __restrict__ dst,
                              const float* __restrict__ avg,
                              float* __restrict__ out,
                              int E) {
    int i4 = blockIdx.x * blockDim.x + threadIdx.x;
    int base = i4 * 4;
    if (base + 3 < E) {
        nint4 s = __builtin_nontemporal_load((const nint4*)(src + base));
        nint4 d = __builtin_nontemporal_load((const nint4*)(dst + base));
        nfloat4 m = __builtin_nontemporal_load((const nfloat4*)(mask + base));
        nfloat4 o;
        o.x = (1.0f - GAMMA) * m.x + GAMMA * 0.5f * (avg[s.x] + avg[d.x]);
        o.y = (1.0f - GAMMA) * m.y + GAMMA * 0.5f * (avg[s.y] + avg[d.y]);
        o.z = (1.0f - GAMMA) * m.z + GAMMA * 0.5f * (avg[s.z] + avg[d.z]);
        o.w = (1.0f - GAMMA) * m.w + GAMMA * 0.5f * (avg[s.w] + avg[d.w]);
        __builtin_nontemporal_store(o, (nfloat4*)(out + base));
    } else {
        for (int i = base; i < E; ++i) {
            out[i] = (1.0f - GAMMA) * mask[i] + GAMMA * 0.5f * (avg[src[i]] + avg[dst[i]]);
        }
    }
}

// ---------- fallback path (small ws): packed 64-bit atomic scatter ---------

#define FIX_SCALE64 16777216.0f
#define SUM_MASK64 0xFFFFFFFFFFULL
#define CNT_ONE64 (1ULL << 40)

__global__ void scatter_sum_kernel(const float* __restrict__ mask,
                                   const int* __restrict__ src,
                                   unsigned long long* __restrict__ acc,
                                   int E) {
    int i4 = blockIdx.x * blockDim.x + threadIdx.x;
    int base = i4 * 4;
    if (base + 3 < E) {
        nint4 s = *(const nint4*)(src + base);
        nfloat4 m = *(const nfloat4*)(mask + base);
        atomicAdd(&acc[s.x], CNT_ONE64 | (unsigned long long)(unsigned)(m.x * FIX_SCALE64 + 0.5f));
        atomicAdd(&acc[s.y], CNT_ONE64 | (unsigned long long)(unsigned)(m.y * FIX_SCALE64 + 0.5f));
        atomicAdd(&acc[s.z], CNT_ONE64 | (unsigned long long)(unsigned)(m.z * FIX_SCALE64 + 0.5f));
        atomicAdd(&acc[s.w], CNT_ONE64 | (unsigned long long)(unsigned)(m.w * FIX_SCALE64 + 0.5f));
    } else {
        for (int i = base; i < E; ++i) {
            atomicAdd(&acc[src[i]],
                      CNT_ONE64 | (unsigned long long)(unsigned)(mask[i] * FIX_SCALE64 + 0.5f));
        }
    }
}

__global__ void avg_kernel(const unsigned long long* __restrict__ acc,
                           float* __restrict__ avg,
                           int N) {
    int i = blockIdx.x * blockDim.x + threadIdx.x;
    if (i < N) {
        unsigned long long pk = acc[i];
        float cnt = (float)(unsigned)(pk >> 40);
        float sum = (float)(pk & SUM_MASK64) * (1.0f / FIX_SCALE64);
        avg[i] = sum / fmaxf(cnt, 1.0f);
    }
}

// ---------------------------------------------------------------------------

extern "C" void kernel_launch(void* const* d_in, const int* in_sizes, int n_in,
                              void* d_out, int out_size, void* d_ws, size_t ws_size,
                              hipStream_t stream) {
    const float* mask = (const float*)d_in[0];
    const int* edge_index = (const int*)d_in[1];
    const int E = in_sizes[0];            // 6,400,000
    const int* src = edge_index;          // row 0
    const int* dst = edge_index + E;      // row 1
    float* out = (float*)d_out;

    const int B = 256;
    const int E4 = (E + 3) / 4;

    // Layout: [partials: C*P*NPART u32][avg: NUM_NODES f32]
    // C=96 -> grid 768 = 3 blocks/CU * 256 CUs, fully co-resident.
    const size_t avg_bytes = (size_t)NUM_NODES * sizeof(float);
    const size_t table_bytes = (size_t)P * NPART * sizeof(unsigned);
    int C = 0;
    if (ws_size > avg_bytes + table_bytes) {
        C = (int)((ws_size - avg_bytes) / table_bytes);
        if (C > 96) C = 96;
        C &= ~7;                          // swizzle needs C % 8 == 0
    }

    if (C >= 16) {
        unsigned* partials = (unsigned*)d_ws;
        float* avg = (float*)((char*)d_ws + (size_t)C * table_bytes);
        int CS = (((E + C - 1) / C) + 3) & ~3;   // multiple of 4 for int4 align
        part_scatter_kernel<<<C * P, B, 0, stream>>>(mask, src, partials, E, CS, C);
        reduce_avg_kernel<<<(NUM_NODES + B - 1) / B, B, 0, stream>>>(partials, avg, C);
        smooth_kernel<<<(E4 + B - 1) / B, B, 0, stream>>>(mask, src, dst, avg, out, E);
    } else {
        unsigned long long* acc = (unsigned long long*)d_ws;   // [NUM_NODES]
        float* avg = (float*)(acc + NUM_NODES);                // [NUM_NODES]
        (void)hipMemsetAsync(d_ws, 0, NUM_NODES * sizeof(unsigned long long), stream);
        scatter_sum_kernel<<<(E4 + B - 1) / B, B, 0, stream>>>(mask, src, acc, E);
        avg_kernel<<<(NUM_NODES + B - 1) / B, B, 0, stream>>>(acc, avg, NUM_NODES);
        smooth_kernel<<<(E4 + B - 1) / B, B, 0, stream>>>(mask, src, dst, avg, out, E);
    }
}

// Round 6
// 230.884 us; speedup vs baseline: 1.0630x; 1.0630x over previous
//
#include <hip/hip_runtime.h>

#define NUM_NODES 100000
#define P 8
#define NPART 12500             // NUM_NODES / P
#define GAMMA 0.5f

// Native vector types for nontemporal builtins (HIP int4/float4 are structs
// and are rejected by __builtin_nontemporal_*).
typedef int   nint4   __attribute__((ext_vector_type(4)));
typedef float nfloat4 __attribute__((ext_vector_type(4)));
typedef unsigned nuint4 __attribute__((ext_vector_type(4)));

// 32-bit packed partial: bits [31:22] = count (max 1023), bits [21:0] =
// fixed-point sum, scale 2^14. mask in [0,1), per-chunk node degree ~1.
#define SCALE 16384.0f
#define INV_SCALE (1.0f / 16384.0f)
#define CNT_ONE (1u << 22)
#define SUM_MASK ((1u << 22) - 1)

// ---------- main path: partitioned LDS scatter, no global atomics ----------

// XCD-aware mapping (R5, kept): all 8 partition-blocks of a chunk land on the
// same XCD -> chunk stream fetched once into that XCD's L2 (FETCH 200->25MB).
// R6: block=512 @ 50KB LDS -> still 3 blocks/CU, but 24 waves/CU (was 12) to
// hide LDS-atomic/branch/load latency (VALUBusy was only 16%).
__global__ void __launch_bounds__(512)
part_scatter_kernel(const float* __restrict__ mask,
                    const int* __restrict__ src,
                    unsigned* __restrict__ partials,
                    int E, int CS, int C) {
    __shared__ unsigned tab[NPART];
    const int g = blockIdx.x;
    const int cpx = C >> 3;               // chunks per XCD
    const int xcd = g & 7;
    const int j = g >> 3;
    const int c = xcd * cpx + (j % cpx);
    const int p = j / cpx;
    const int pbase = p * NPART;

    for (int t = threadIdx.x; t < NPART; t += blockDim.x) tab[t] = 0u;
    __syncthreads();

    const int start = c * CS;             // CS % 4 == 0 -> 16B-aligned int4
    const int end = min(E, start + CS);
    const int nquads = (end - start) >> 2;

    for (int q = threadIdx.x; q < nquads; q += blockDim.x) {
        const int i = start + q * 4;
        nint4 s = *(const nint4*)(src + i);
        nfloat4 m = *(const nfloat4*)(mask + i);
        int sx = s.x - pbase;
        if ((unsigned)sx < NPART) atomicAdd(&tab[sx], CNT_ONE | (unsigned)(m.x * SCALE + 0.5f));
        int sy = s.y - pbase;
        if ((unsigned)sy < NPART) atomicAdd(&tab[sy], CNT_ONE | (unsigned)(m.y * SCALE + 0.5f));
        int sz = s.z - pbase;
        if ((unsigned)sz < NPART) atomicAdd(&tab[sz], CNT_ONE | (unsigned)(m.z * SCALE + 0.5f));
        int sw = s.w - pbase;
        if ((unsigned)sw < NPART) atomicAdd(&tab[sw], CNT_ONE | (unsigned)(m.w * SCALE + 0.5f));
    }
    for (int i = start + nquads * 4 + threadIdx.x; i < end; i += blockDim.x) {
        int sx = src[i] - pbase;
        if ((unsigned)sx < NPART)
            atomicAdd(&tab[sx], CNT_ONE | (unsigned)(mask[i] * SCALE + 0.5f));
    }

    __syncthreads();
    // logical (c,p) index; nontemporal store: written once, read once.
    unsigned* dstp = partials + ((size_t)c * P + p) * NPART;
    for (int t = threadIdx.x; t < NPART; t += blockDim.x)
        __builtin_nontemporal_store(tab[t], dstp + t);
}

// K2: reduce C partials per node. 4 nodes/thread, uint4 loads along loc
// (NPART % 4 == 0, slice base 50000B is 16B-aligned, partitions never
// straddle a 4-node group).
__global__ void reduce_avg_kernel(const unsigned* __restrict__ partials,
                                  float* __restrict__ avg,
                                  int C) {
    int n0 = (blockIdx.x * blockDim.x + threadIdx.x) * 4;
    if (n0 < NUM_NODES) {
        int p = n0 / NPART;
        int loc = n0 - p * NPART;
        const unsigned* base = partials + (size_t)p * NPART + loc;
        const size_t stride = (size_t)P * NPART;
        unsigned cnt0 = 0, cnt1 = 0, cnt2 = 0, cnt3 = 0;
        unsigned sum0 = 0, sum1 = 0, sum2 = 0, sum3 = 0;
        for (int c = 0; c < C; ++c) {
            nuint4 v = __builtin_nontemporal_load((const nuint4*)(base + (size_t)c * stride));
            cnt0 += v.x >> 22; sum0 += v.x & SUM_MASK;
            cnt1 += v.y >> 22; sum1 += v.y & SUM_MASK;
            cnt2 += v.z >> 22; sum2 += v.z & SUM_MASK;
            cnt3 += v.w >> 22; sum3 += v.w & SUM_MASK;
        }
        nfloat4 a;
        a.x = ((float)sum0 * INV_SCALE) / fmaxf((float)cnt0, 1.0f);
        a.y = ((float)sum1 * INV_SCALE) / fmaxf((float)cnt1, 1.0f);
        a.z = ((float)sum2 * INV_SCALE) / fmaxf((float)cnt2, 1.0f);
        a.w = ((float)sum3 * INV_SCALE) / fmaxf((float)cnt3, 1.0f);
        *(nfloat4*)(avg + n0) = a;
    }
}

// K3: gather endpoint means, blend with original mask. Plain cached loads
// (R5 nt loads regressed smooth+reduce ~26us); nt only on the out store.
__global__ void smooth_kernel(const float* __restrict__ mask,
                              const int* __restrict__ src,
                              const int* __restrict__ dst,
                              const float* __restrict__ avg,
                              float* __restrict__ out,
                              int E) {
    int i4 = blockIdx.x * blockDim.x + threadIdx.x;
    int base = i4 * 4;
    if (base + 3 < E) {
        nint4 s = *(const nint4*)(src + base);
        nint4 d = *(const nint4*)(dst + base);
        nfloat4 m = *(const nfloat4*)(mask + base);
        nfloat4 o;
        o.x = (1.0f - GAMMA) * m.x + GAMMA * 0.5f * (avg[s.x] + avg[d.x]);
        o.y = (1.0f - GAMMA) * m.y + GAMMA * 0.5f * (avg[s.y] + avg[d.y]);
        o.z = (1.0f - GAMMA) * m.z + GAMMA * 0.5f * (avg[s.z] + avg[d.z]);
        o.w = (1.0f - GAMMA) * m.w + GAMMA * 0.5f * (avg[s.w] + avg[d.w]);
        __builtin_nontemporal_store(o, (nfloat4*)(out + base));
    } else {
        for (int i = base; i < E; ++i) {
            out[i] = (1.0f - GAMMA) * mask[i] + GAMMA * 0.5f * (avg[src[i]] + avg[dst[i]]);
        }
    }
}

// ---------- fallback path (small ws): packed 64-bit atomic scatter ---------

#define FIX_SCALE64 16777216.0f
#define SUM_MASK64 0xFFFFFFFFFFULL
#define CNT_ONE64 (1ULL << 40)

__global__ void scatter_sum_kernel(const float* __restrict__ mask,
                                   const int* __restrict__ src,
                                   unsigned long long* __restrict__ acc,
                                   int E) {
    int i4 = blockIdx.x * blockDim.x + threadIdx.x;
    int base = i4 * 4;
    if (base + 3 < E) {
        nint4 s = *(const nint4*)(src + base);
        nfloat4 m = *(const nfloat4*)(mask + base);
        atomicAdd(&acc[s.x], CNT_ONE64 | (unsigned long long)(unsigned)(m.x * FIX_SCALE64 + 0.5f));
        atomicAdd(&acc[s.y], CNT_ONE64 | (unsigned long long)(unsigned)(m.y * FIX_SCALE64 + 0.5f));
        atomicAdd(&acc[s.z], CNT_ONE64 | (unsigned long long)(unsigned)(m.z * FIX_SCALE64 + 0.5f));
        atomicAdd(&acc[s.w], CNT_ONE64 | (unsigned long long)(unsigned)(m.w * FIX_SCALE64 + 0.5f));
    } else {
        for (int i = base; i < E; ++i) {
            atomicAdd(&acc[src[i]],
                      CNT_ONE64 | (unsigned long long)(unsigned)(mask[i] * FIX_SCALE64 + 0.5f));
        }
    }
}

__global__ void avg_kernel(const unsigned long long* __restrict__ acc,
                           float* __restrict__ avg,
                           int N) {
    int i = blockIdx.x * blockDim.x + threadIdx.x;
    if (i < N) {
        unsigned long long pk = acc[i];
        float cnt = (float)(unsigned)(pk >> 40);
        float sum = (float)(pk & SUM_MASK64) * (1.0f / FIX_SCALE64);
        avg[i] = sum / fmaxf(cnt, 1.0f);
    }
}

// ---------------------------------------------------------------------------

extern "C" void kernel_launch(void* const* d_in, const int* in_sizes, int n_in,
                              void* d_out, int out_size, void* d_ws, size_t ws_size,
                              hipStream_t stream) {
    const float* mask = (const float*)d_in[0];
    const int* edge_index = (const int*)d_in[1];
    const int E = in_sizes[0];            // 6,400,000
    const int* src = edge_index;          // row 0
    const int* dst = edge_index + E;      // row 1
    float* out = (float*)d_out;

    const int B = 256;
    const int E4 = (E + 3) / 4;

    // Layout: [partials: C*P*NPART u32][avg: NUM_NODES f32]
    // C=96, block=512 -> grid 768 = 3 blocks/CU (LDS-limited), 24 waves/CU.
    const size_t avg_bytes = (size_t)NUM_NODES * sizeof(float);
    const size_t table_bytes = (size_t)P * NPART * sizeof(unsigned);
    int C = 0;
    if (ws_size > avg_bytes + table_bytes) {
        C = (int)((ws_size - avg_bytes) / table_bytes);
        if (C > 96) C = 96;
        C &= ~7;                          // swizzle needs C % 8 == 0
    }

    if (C >= 16) {
        unsigned* partials = (unsigned*)d_ws;
        float* avg = (float*)((char*)d_ws + (size_t)C * table_bytes);
        int CS = (((E + C - 1) / C) + 3) & ~3;   // multiple of 4 for int4 align
        part_scatter_kernel<<<C * P, 512, 0, stream>>>(mask, src, partials, E, CS, C);
        const int nthreads = (NUM_NODES + 3) / 4;
        reduce_avg_kernel<<<(nthreads + B - 1) / B, B, 0, stream>>>(partials, avg, C);
        smooth_kernel<<<(E4 + B - 1) / B, B, 0, stream>>>(mask, src, dst, avg, out, E);
    } else {
        unsigned long long* acc = (unsigned long long*)d_ws;   // [NUM_NODES]
        float* avg = (float*)(acc + NUM_NODES);                // [NUM_NODES]
        (void)hipMemsetAsync(d_ws, 0, NUM_NODES * sizeof(unsigned long long), stream);
        scatter_sum_kernel<<<(E4 + B - 1) / B, B, 0, stream>>>(mask, src, acc, E);
        avg_kernel<<<(NUM_NODES + B - 1) / B, B, 0, stream>>>(acc, avg, NUM_NODES);
        smooth_kernel<<<(E4 + B - 1) / B, B, 0, stream>>>(mask, src, dst, avg, out, E);
    }
}

// Round 7
// 197.129 us; speedup vs baseline: 1.2450x; 1.1712x over previous
//
#include <hip/hip_runtime.h>

#define NUM_NODES 100000
#define P 8
#define NPART 12500             // NUM_NODES / P
#define GAMMA 0.5f

// Native vector types (HIP int4/float4 are structs; rejected by
// __builtin_nontemporal_* and worse for ext-vector codegen).
typedef int   nint4   __attribute__((ext_vector_type(4)));
typedef float nfloat4 __attribute__((ext_vector_type(4)));
typedef unsigned nuint4 __attribute__((ext_vector_type(4)));

// 32-bit packed partial: bits [31:22] = count (max 1023), bits [21:0] =
// fixed-point sum, scale 2^14. mask in [0,1), per-chunk node degree ~2.
#define SCALE 16384.0f
#define INV_SCALE (1.0f / 16384.0f)
#define CNT_ONE (1u << 22)
#define SUM_MASK ((1u << 22) - 1)

// ---------- main path: partitioned LDS scatter, no global atomics ----------

// XCD swizzle (R5): all 8 partition-blocks of a chunk on the same XCD ->
// chunk stream fetched into that XCD's L2 once (FETCH 200->25MB).
// R7: block=1024, C=64 -> grid 512 = 2 blocks/CU, 32 waves/CU (HW max),
// LDS 2*50KB = 100KB/CU. Latency-bound kernel -> more waves.
__global__ void __launch_bounds__(1024)
part_scatter_kernel(const float* __restrict__ mask,
                    const int* __restrict__ src,
                    unsigned* __restrict__ partials,
                    int E, int CS, int C) {
    __shared__ unsigned tab[NPART];
    const int g = blockIdx.x;
    const int cpx = C >> 3;               // chunks per XCD
    const int xcd = g & 7;
    const int j = g >> 3;
    const int c = xcd * cpx + (j % cpx);
    const int p = j / cpx;
    const int pbase = p * NPART;

    for (int t = threadIdx.x; t < NPART; t += blockDim.x) tab[t] = 0u;
    __syncthreads();

    const int start = c * CS;             // CS % 4 == 0 -> 16B-aligned int4
    const int end = min(E, start + CS);
    const int nquads = (end - start) >> 2;

    for (int q = threadIdx.x; q < nquads; q += blockDim.x) {
        const int i = start + q * 4;
        nint4 s = *(const nint4*)(src + i);
        nfloat4 m = *(const nfloat4*)(mask + i);
        int sx = s.x - pbase;
        if ((unsigned)sx < NPART) atomicAdd(&tab[sx], CNT_ONE | (unsigned)(m.x * SCALE + 0.5f));
        int sy = s.y - pbase;
        if ((unsigned)sy < NPART) atomicAdd(&tab[sy], CNT_ONE | (unsigned)(m.y * SCALE + 0.5f));
        int sz = s.z - pbase;
        if ((unsigned)sz < NPART) atomicAdd(&tab[sz], CNT_ONE | (unsigned)(m.z * SCALE + 0.5f));
        int sw = s.w - pbase;
        if ((unsigned)sw < NPART) atomicAdd(&tab[sw], CNT_ONE | (unsigned)(m.w * SCALE + 0.5f));
    }
    for (int i = start + nquads * 4 + threadIdx.x; i < end; i += blockDim.x) {
        int sx = src[i] - pbase;
        if ((unsigned)sx < NPART)
            atomicAdd(&tab[sx], CNT_ONE | (unsigned)(mask[i] * SCALE + 0.5f));
    }

    __syncthreads();
    // logical (c,p) index; nt store: written once, read once by reduce.
    unsigned* dstp = partials + ((size_t)c * P + p) * NPART;
    for (int t = threadIdx.x; t < NPART; t += blockDim.x)
        __builtin_nontemporal_store(tab[t], dstp + t);
}

// K2: reduce C partials per node. 4 nodes/thread, uint4 loads, unrolled for
// deep MLP (grid is only ~98 blocks; per-thread ILP is the latency hider).
// Plain cached loads (nt loads regressed in R5).
__global__ void reduce_avg_kernel(const unsigned* __restrict__ partials,
                                  float* __restrict__ avg,
                                  int C) {
    int n0 = (blockIdx.x * blockDim.x + threadIdx.x) * 4;
    if (n0 < NUM_NODES) {
        int p = n0 / NPART;
        int loc = n0 - p * NPART;
        const unsigned* base = partials + (size_t)p * NPART + loc;
        const size_t stride = (size_t)P * NPART;
        unsigned cnt0 = 0, cnt1 = 0, cnt2 = 0, cnt3 = 0;
        unsigned sum0 = 0, sum1 = 0, sum2 = 0, sum3 = 0;
#pragma unroll 8
        for (int c = 0; c < C; ++c) {
            nuint4 v = *(const nuint4*)(base + (size_t)c * stride);
            cnt0 += v.x >> 22; sum0 += v.x & SUM_MASK;
            cnt1 += v.y >> 22; sum1 += v.y & SUM_MASK;
            cnt2 += v.z >> 22; sum2 += v.z & SUM_MASK;
            cnt3 += v.w >> 22; sum3 += v.w & SUM_MASK;
        }
        nfloat4 a;
        a.x = ((float)sum0 * INV_SCALE) / fmaxf((float)cnt0, 1.0f);
        a.y = ((float)sum1 * INV_SCALE) / fmaxf((float)cnt1, 1.0f);
        a.z = ((float)sum2 * INV_SCALE) / fmaxf((float)cnt2, 1.0f);
        a.w = ((float)sum3 * INV_SCALE) / fmaxf((float)cnt3, 1.0f);
        *(nfloat4*)(avg + n0) = a;
    }
}

// K3: gather endpoint means, blend with original mask. 8 edges/thread ->
// 16 outstanding random gathers per thread (gather-latency hiding test).
// Plain cached loads for streams; nt only on the write-once out store.
__global__ void smooth_kernel(const float* __restrict__ mask,
                              const int* __restrict__ src,
                              const int* __restrict__ dst,
                              const float* __restrict__ avg,
                              float* __restrict__ out,
                              int E) {
    int tid = blockIdx.x * blockDim.x + threadIdx.x;
    int base = tid * 8;
    if (base + 7 < E) {
        nint4 s0 = *(const nint4*)(src + base);
        nint4 s1 = *(const nint4*)(src + base + 4);
        nint4 d0 = *(const nint4*)(dst + base);
        nint4 d1 = *(const nint4*)(dst + base + 4);
        nfloat4 m0 = *(const nfloat4*)(mask + base);
        nfloat4 m1 = *(const nfloat4*)(mask + base + 4);
        nfloat4 o0, o1;
        o0.x = (1.0f - GAMMA) * m0.x + GAMMA * 0.5f * (avg[s0.x] + avg[d0.x]);
        o0.y = (1.0f - GAMMA) * m0.y + GAMMA * 0.5f * (avg[s0.y] + avg[d0.y]);
        o0.z = (1.0f - GAMMA) * m0.z + GAMMA * 0.5f * (avg[s0.z] + avg[d0.z]);
        o0.w = (1.0f - GAMMA) * m0.w + GAMMA * 0.5f * (avg[s0.w] + avg[d0.w]);
        o1.x = (1.0f - GAMMA) * m1.x + GAMMA * 0.5f * (avg[s1.x] + avg[d1.x]);
        o1.y = (1.0f - GAMMA) * m1.y + GAMMA * 0.5f * (avg[s1.y] + avg[d1.y]);
        o1.z = (1.0f - GAMMA) * m1.z + GAMMA * 0.5f * (avg[s1.z] + avg[d1.z]);
        o1.w = (1.0f - GAMMA) * m1.w + GAMMA * 0.5f * (avg[s1.w] + avg[d1.w]);
        __builtin_nontemporal_store(o0, (nfloat4*)(out + base));
        __builtin_nontemporal_store(o1, (nfloat4*)(out + base + 4));
    } else {
        for (int i = base; i < E; ++i) {
            out[i] = (1.0f - GAMMA) * mask[i] + GAMMA * 0.5f * (avg[src[i]] + avg[dst[i]]);
        }
    }
}

// ---------- fallback path (small ws): packed 64-bit atomic scatter ---------

#define FIX_SCALE64 16777216.0f
#define SUM_MASK64 0xFFFFFFFFFFULL
#define CNT_ONE64 (1ULL << 40)

__global__ void scatter_sum_kernel(const float* __restrict__ mask,
                                   const int* __restrict__ src,
                                   unsigned long long* __restrict__ acc,
                                   int E) {
    int i4 = blockIdx.x * blockDim.x + threadIdx.x;
    int base = i4 * 4;
    if (base + 3 < E) {
        nint4 s = *(const nint4*)(src + base);
        nfloat4 m = *(const nfloat4*)(mask + base);
        atomicAdd(&acc[s.x], CNT_ONE64 | (unsigned long long)(unsigned)(m.x * FIX_SCALE64 + 0.5f));
        atomicAdd(&acc[s.y], CNT_ONE64 | (unsigned long long)(unsigned)(m.y * FIX_SCALE64 + 0.5f));
        atomicAdd(&acc[s.z], CNT_ONE64 | (unsigned long long)(unsigned)(m.z * FIX_SCALE64 + 0.5f));
        atomicAdd(&acc[s.w], CNT_ONE64 | (unsigned long long)(unsigned)(m.w * FIX_SCALE64 + 0.5f));
    } else {
        for (int i = base; i < E; ++i) {
            atomicAdd(&acc[src[i]],
                      CNT_ONE64 | (unsigned long long)(unsigned)(mask[i] * FIX_SCALE64 + 0.5f));
        }
    }
}

__global__ void avg_kernel(const unsigned long long* __restrict__ acc,
                           float* __restrict__ avg,
                           int N) {
    int i = blockIdx.x * blockDim.x + threadIdx.x;
    if (i < N) {
        unsigned long long pk = acc[i];
        float cnt = (float)(unsigned)(pk >> 40);
        float sum = (float)(pk & SUM_MASK64) * (1.0f / FIX_SCALE64);
        avg[i] = sum / fmaxf(cnt, 1.0f);
    }
}

// ---------------------------------------------------------------------------

extern "C" void kernel_launch(void* const* d_in, const int* in_sizes, int n_in,
                              void* d_out, int out_size, void* d_ws, size_t ws_size,
                              hipStream_t stream) {
    const float* mask = (const float*)d_in[0];
    const int* edge_index = (const int*)d_in[1];
    const int E = in_sizes[0];            // 6,400,000
    const int* src = edge_index;          // row 0
    const int* dst = edge_index + E;      // row 1
    float* out = (float*)d_out;

    const int B = 256;

    // Layout: [partials: C*P*NPART u32][avg: NUM_NODES f32]
    // C=64, block=1024 -> grid 512 = 2 blocks/CU, 32 waves/CU (HW max).
    const size_t avg_bytes = (size_t)NUM_NODES * sizeof(float);
    const size_t table_bytes = (size_t)P * NPART * sizeof(unsigned);
    int C = 0;
    if (ws_size > avg_bytes + table_bytes) {
        C = (int)((ws_size - avg_bytes) / table_bytes);
        if (C > 64) C = 64;
        C &= ~7;                          // swizzle needs C % 8 == 0
    }

    if (C >= 16) {
        unsigned* partials = (unsigned*)d_ws;
        float* avg = (float*)((char*)d_ws + (size_t)C * table_bytes);
        int CS = (((E + C - 1) / C) + 3) & ~3;   // multiple of 4 for int4 align
        part_scatter_kernel<<<C * P, 1024, 0, stream>>>(mask, src, partials, E, CS, C);
        const int nthreads = (NUM_NODES + 3) / 4;
        reduce_avg_kernel<<<(nthreads + B - 1) / B, B, 0, stream>>>(partials, avg, C);
        const int E8 = (E + 7) / 8;
        smooth_kernel<<<(E8 + B - 1) / B, B, 0, stream>>>(mask, src, dst, avg, out, E);
    } else {
        unsigned long long* acc = (unsigned long long*)d_ws;   // [NUM_NODES]
        float* avg = (float*)(acc + NUM_NODES);                // [NUM_NODES]
        (void)hipMemsetAsync(d_ws, 0, NUM_NODES * sizeof(unsigned long long), stream);
        const int E4 = (E + 3) / 4;
        scatter_sum_kernel<<<(E4 + B - 1) / B, B, 0, stream>>>(mask, src, acc, E);
        avg_kernel<<<(NUM_NODES + B - 1) / B, B, 0, stream>>>(acc, avg, NUM_NODES);
        smooth_kernel<<<(((E + 7) / 8) + B - 1) / B, B, 0, stream>>>(mask, src, dst, avg, out, E);
    }
}